// Round 19
// baseline (50.112 us; speedup 1.0000x reference)
//
#include <hip/hip_runtime.h>
#include <hip/hip_bf16.h>

#define CDIM   64
#define HWDIM  4096
#define NCODES 1024
#define NELEM  8388608   // 32*64*64*64 = N*C
#define NBLOCK 1024      // 131072 rows / 128 rows-per-block; ~4 blocks/CU
#define NPART  (NBLOCK * 8)
#define LDSSZ  (65536 + 16 * 68 * 4)   // 64 KB fp8 codebook + padded bias

typedef float f32x4 __attribute__((ext_vector_type(4)));

__device__ __forceinline__ unsigned asu(float f) {
    union { float f; unsigned u; } v; v.f = f; return v.u;
}
__device__ __forceinline__ float asf(unsigned u) {
    union { unsigned u; float f; } v; v.u = u; return v.f;
}
__device__ __forceinline__ void gload_lds16(const void* g, void* l) {
    __builtin_amdgcn_global_load_lds(
        (const __attribute__((address_space(1))) void*)g,
        (__attribute__((address_space(3))) void*)l, 16, 0, 0);
}

// prep: Eb = fp8_e4m3(16384 * E) (1 B/elem, row-major), biasS = -8192*||e||^2.
// Score S = z . (2^14 e) - 2^13 ||e||^2 = 2^13 (2 z.e - ||e||^2);
// argmax S == argmin ||z-e||^2; d = ||z||^2 - S * 2^-13.
__global__ void vq_prep(const float* __restrict__ E,
                        unsigned char* __restrict__ Eb,
                        float* __restrict__ biasS) {
    int t = blockIdx.x * blockDim.x + threadIdx.x;   // one thread per code
    if (t < NCODES) {
        const float4* ev = (const float4*)(E + t * CDIM);
        float s = 0.f;
        int dw[16];
        #pragma unroll
        for (int i = 0; i < 16; ++i) {
            float4 v = ev[i];
            s = fmaf(v.x, v.x, s); s = fmaf(v.y, v.y, s);
            s = fmaf(v.z, v.z, s); s = fmaf(v.w, v.w, s);
            int d = __builtin_amdgcn_cvt_pk_fp8_f32(v.x * 16384.f, v.y * 16384.f, 0, false);
            d     = __builtin_amdgcn_cvt_pk_fp8_f32(v.z * 16384.f, v.w * 16384.f, d, true);
            dw[i] = d;
        }
        int4* dst = (int4*)(Eb + t * CDIM);
        #pragma unroll
        for (int k = 0; k < 4; ++k) {
            int4 q; q.x = dw[4*k]; q.y = dw[4*k+1]; q.z = dw[4*k+2]; q.w = dw[4*k+3];
            dst[k] = q;
        }
        biasS[t] = -8192.f * s;
    }
}

// 512 thr = 8 waves x 16 rows (128 rows/block), grid 1024: 68.3 KB LDS ->
// 2 RESIDENT blocks/CU + 2 queued -> cross-block phase overlap (the lever
// R6-R18 never had: at 1 block/CU, prologue/K-loop/epilogue serialize).
// fp8 codebook (64 KB) staged via async global_load_lds with 16B-granular
// XOR swizzle (LDS slot c of row r holds source chunk c^(r&3); involution,
// both-sides rule). K-loop: ds_read_b64 pairs (conflict-free by bank math:
// 512 B/wave over 32 banks, 4 accesses each), 2 fp8 MFMAs (rate = bf16),
// packed-key argmax. Epilogue gathers exact fp32 E from global.
__global__ __launch_bounds__(512)
void vq_main(const float* __restrict__ z,
             const float* __restrict__ E,
             const unsigned char* __restrict__ Eb,
             const float* __restrict__ biasS,
             float* __restrict__ out,
             float* __restrict__ partial) {
    extern __shared__ char smem[];
    unsigned char* sEb = (unsigned char*)smem;             // 64 KB swizzled
    float (*sBiasT)[68] = (float(*)[68])(smem + 65536);    // [16][68] padded

    const int lane = threadIdx.x & 63;
    const int wave = threadIdx.x >> 6;   // 0..7
    const int lrow = lane & 15;          // row/code-col within 16-tile
    const int lgrp = lane >> 4;          // k-group 0..3

    const int n0 = blockIdx.x * 128 + wave * 16;  // wave's 16 rows
    const int b  = n0 >> 12;
    const int hw = n0 & 4095;            // 128-aligned block; +15 in batch
    const float* zb   = z   + (size_t)b * (CDIM * HWDIM);
    float*       outb = out + (size_t)b * (CDIM * HWDIM);

    // ---- stage fp8 codebook via async DMA: 4096 16B chunks, 8 per thread.
    // LDS linear dest; inverse-swizzled global source (chunk s^(row&3)).
    #pragma unroll
    for (int i = 0; i < 8; ++i) {
        const int cid = i * 512 + (int)threadIdx.x;
        const int row = cid >> 2;
        const int s16 = cid & 3;
        const unsigned char* g = Eb + row * CDIM + ((s16 ^ (row & 3)) << 4);
        gload_lds16(g, sEb + cid * 16);
    }
    {   // bias, transposed: sBiasT[code&15][code>>4]
        const int i = (int)threadIdx.x;
        sBiasT[i & 15][i >> 4] = biasS[i];
        const int i2 = i + 512;
        sBiasT[i2 & 15][i2 >> 4] = biasS[i2];
    }

    // A fragment: row lrow, k = 32s + 8g + j; z -> fp8 unscaled (|z|<~5).
    float szz = 0.f;
    long a0, a1;
    {
        float zv[8];
        #pragma unroll
        for (int j = 0; j < 8; ++j) {
            float v = zb[(8 * lgrp + j) * HWDIM + hw + lrow];
            szz = fmaf(v, v, szz); zv[j] = v;
        }
        int dlo = __builtin_amdgcn_cvt_pk_fp8_f32(zv[0], zv[1], 0, false);
        dlo     = __builtin_amdgcn_cvt_pk_fp8_f32(zv[2], zv[3], dlo, true);
        int dhi = __builtin_amdgcn_cvt_pk_fp8_f32(zv[4], zv[5], 0, false);
        dhi     = __builtin_amdgcn_cvt_pk_fp8_f32(zv[6], zv[7], dhi, true);
        a0 = (long)(unsigned)dlo | ((long)dhi << 32);
        #pragma unroll
        for (int j = 0; j < 8; ++j) {
            float v = zb[(32 + 8 * lgrp + j) * HWDIM + hw + lrow];
            szz = fmaf(v, v, szz); zv[j] = v;
        }
        dlo = __builtin_amdgcn_cvt_pk_fp8_f32(zv[0], zv[1], 0, false);
        dlo = __builtin_amdgcn_cvt_pk_fp8_f32(zv[2], zv[3], dlo, true);
        dhi = __builtin_amdgcn_cvt_pk_fp8_f32(zv[4], zv[5], 0, false);
        dhi = __builtin_amdgcn_cvt_pk_fp8_f32(zv[6], zv[7], dhi, true);
        a1 = (long)(unsigned)dlo | ((long)dhi << 32);
    }

    float run[4] = {-3.0e38f, -3.0e38f, -3.0e38f, -3.0e38f};

    __syncthreads();   // the ONLY barrier: DMA + bias complete

    // loop-invariant swizzled byte offsets (r&3 == lrow&3 for all kt)
    const int ch0 = (((lgrp >> 1) ^ (lrow & 3)) << 4) + ((lgrp & 1) << 3);
    const char* pa = (const char*)sEb + lrow * 64 + ch0;          // k 0..31
    const char* pb = (const char*)sEb + lrow * 64 + (ch0 ^ 32);   // k 32..63
    const float* pbias = &sBiasT[lrow][0];
    unsigned codev = (unsigned)lrow;

    for (int ch = 0; ch < 8; ++ch) {
        f32x4 bq0 = *(const f32x4*)(pbias);       // biases kt = ch*8+0..3
        f32x4 bq1 = *(const f32x4*)(pbias + 4);   // biases kt = ch*8+4..7
        #pragma unroll
        for (int j = 0; j < 8; ++j) {
            long b0 = *(const long*)(pa + j * 1024);
            long b1 = *(const long*)(pb + j * 1024);
            const float bv = (j < 4) ? bq0[j] : bq1[j - 4];   // static idx
            f32x4 ci = {bv, bv, bv, bv};
            f32x4 acc = __builtin_amdgcn_mfma_f32_16x16x32_fp8_fp8(a0, b0, ci, 0, 0, 0);
            acc = __builtin_amdgcn_mfma_f32_16x16x32_fp8_fp8(a1, b1, acc, 0, 0, 0);
            const unsigned code = codev + (unsigned)(j * 16);
            #pragma unroll
            for (int r = 0; r < 4; ++r)
                run[r] = fmaxf(run[r], asf((asu(acc[r]) & 0xFFFFFC00u) | code));
        }
        pa += 8192; pb += 8192; pbias += 8; codev += 128;
    }

    // reduce packed keys across the 16 code-columns (lrow lanes): pure max
    #pragma unroll
    for (int m = 1; m <= 8; m <<= 1)
        #pragma unroll
        for (int r = 0; r < 4; ++r)
            run[r] = fmaxf(run[r], __shfl_xor(run[r], m, 64));

    // redistribute: lane (lrow,g) holds rows 4g+r; thread for row lrow
    int idxe;
    float kmine;
    {
        const int src = (lrow >> 2) << 4;   // lane with lgrp == lrow>>2
        float g0 = __shfl(run[0], src, 64);
        float g1 = __shfl(run[1], src, 64);
        float g2 = __shfl(run[2], src, 64);
        float g3 = __shfl(run[3], src, 64);
        kmine = (lrow & 2) ? ((lrow & 1) ? g3 : g2)
                           : ((lrow & 1) ? g1 : g0);
        idxe = (int)(asu(kmine) & 1023u);
    }

    // epilogue: gather exact fp32 codebook row from global E, write out
    {
        const f32x4* ep  = (const f32x4*)(E + idxe * CDIM      + 8 * lgrp);
        const f32x4* ep2 = (const f32x4*)(E + idxe * CDIM + 32 + 8 * lgrp);
        f32x4 qa = ep[0], qb = ep[1], qc = ep2[0], qd = ep2[1];
        float* ob = outb + hw + lrow;
        #pragma unroll
        for (int j = 0; j < 4; ++j) {
            ob[(8 * lgrp + j)          * HWDIM] = qa[j];
            ob[(8 * lgrp + 4 + j)      * HWDIM] = qb[j];
            ob[(32 + 8 * lgrp + j)     * HWDIM] = qc[j];
            ob[(32 + 8 * lgrp + 4 + j) * HWDIM] = qd[j];
        }
    }

    // loss partial: sum z^2 + sum over rows of d_min, d_min = -2^-13 * S
    float dsum = run[0] + run[1] + run[2] + run[3];
    float contrib = szz + ((lrow == 0) ? (-1.220703125e-4f * dsum) : 0.f);
    #pragma unroll
    for (int m = 32; m >= 1; m >>= 1) contrib += __shfl_xor(contrib, m, 64);
    if (lane == 0) partial[blockIdx.x * 8 + wave] = contrib;
}

__global__ __launch_bounds__(1024)
void vq_fin(const float* __restrict__ partial,
            float* __restrict__ out) {
    __shared__ float red[16];
    const int tid = threadIdx.x;   // 1024 threads
    float s = 0.f;
    #pragma unroll
    for (int i = 0; i < NPART / 1024; ++i) s += partial[i * 1024 + tid];
    #pragma unroll
    for (int m = 32; m >= 1; m >>= 1) s += __shfl_xor(s, m, 64);
    if ((tid & 63) == 0) red[tid >> 6] = s;
    __syncthreads();
    if (tid == 0) {
        float tot = 0.f;
        #pragma unroll
        for (int w = 0; w < 16; ++w) tot += red[w];
        out[NELEM] = 1.25f * tot / (float)NELEM;
    }
}

extern "C" void kernel_launch(void* const* d_in, const int* in_sizes, int n_in,
                              void* d_out, int out_size, void* d_ws, size_t ws_size,
                              hipStream_t stream) {
    const float* z = (const float*)d_in[0];
    const float* E = (const float*)d_in[1];
    float* out = (float*)d_out;

    unsigned char* Eb = (unsigned char*)d_ws;                   // 64 KB
    float* biasS      = (float*)((char*)d_ws + 65536);          // 4 KB
    float* partial    = (float*)((char*)d_ws + 65536 + 4096);   // 32 KB

    // allow >64 KB dynamic LDS (host-side attribute; graph-capture safe)
    hipFuncSetAttribute((const void*)vq_main,
                        hipFuncAttributeMaxDynamicSharedMemorySize, LDSSZ);

    vq_prep<<<4, 256, 0, stream>>>(E, Eb, biasS);
    vq_main<<<NBLOCK, 512, LDSSZ, stream>>>(z, E, Eb, biasS, out, partial);
    vq_fin<<<1, 1024, 0, stream>>>(partial, out);
}

// Round 20
// 34.508 us; speedup vs baseline: 1.4522x; 1.4522x over previous
//
#include <hip/hip_runtime.h>
#include <hip/hip_bf16.h>

#define CDIM   64
#define HWDIM  4096
#define NCODES 1024
#define NELEM  8388608   // 32*64*64*64 = N*C
#define NBLOCK 1024      // 131072 rows / 128 rows-per-block; ~4 blocks/CU
#define NPART  (NBLOCK * 8)
#define LDSSZ  (65536 + 16 * 68 * 4)   // 64 KB fp8 codebook + padded bias

typedef float f32x4 __attribute__((ext_vector_type(4)));
typedef long  longx2 __attribute__((ext_vector_type(2)));

__device__ __forceinline__ unsigned asu(float f) {
    union { float f; unsigned u; } v; v.f = f; return v.u;
}
__device__ __forceinline__ float asf(unsigned u) {
    union { unsigned u; float f; } v; v.u = u; return v.f;
}
__device__ __forceinline__ void gload_lds16(const void* g, void* l) {
    __builtin_amdgcn_global_load_lds(
        (const __attribute__((address_space(1))) void*)g,
        (__attribute__((address_space(3))) void*)l, 16, 0, 0);
}

// prep: Eb = fp8_e4m3(16384*E), PRE-PERMUTED + PRE-SWIZZLED per 64B row:
// slot s = g ^ ((row>>1)&3) holds the 16B lane-group g consumes in the
// K-loop: bytes [0..7] = fp8(e[8g..8g+7]), [8..15] = fp8(e[32+8g..32+8g+7]).
// With this layout the main kernel's DMA is LINEAR and its single
// ds_read_b128 per j is bank-conflict-free: within each 8-lane LDS cycle
// group (fixed g, rows r..r+7), banks 16*(r&1)+4*(g^((r>>1)&3)) cover all
// 32 banks exactly once (R19's b64 layout was a 4-way conflict per 16-lane
// group: +12 cyc/read, the measured 1.27e7 conflict counter).
// biasS = -8192*||e||^2; score S = 2^13(2 z.e - ||e||^2); d = ||z||^2 - S/2^13.
__global__ void vq_prep(const float* __restrict__ E,
                        unsigned char* __restrict__ Eb,
                        float* __restrict__ biasS) {
    int t = blockIdx.x * blockDim.x + threadIdx.x;   // one thread per code
    if (t < NCODES) {
        const float4* ev = (const float4*)(E + t * CDIM);
        float s = 0.f;
        #pragma unroll
        for (int g = 0; g < 4; ++g) {
            float4 va = ev[2 * g], vb = ev[2 * g + 1];       // k = 8g..8g+7
            float4 vc = ev[8 + 2 * g], vd = ev[9 + 2 * g];   // k = 32+8g..+7
            s = fmaf(va.x, va.x, s); s = fmaf(va.y, va.y, s);
            s = fmaf(va.z, va.z, s); s = fmaf(va.w, va.w, s);
            s = fmaf(vb.x, vb.x, s); s = fmaf(vb.y, vb.y, s);
            s = fmaf(vb.z, vb.z, s); s = fmaf(vb.w, vb.w, s);
            s = fmaf(vc.x, vc.x, s); s = fmaf(vc.y, vc.y, s);
            s = fmaf(vc.z, vc.z, s); s = fmaf(vc.w, vc.w, s);
            s = fmaf(vd.x, vd.x, s); s = fmaf(vd.y, vd.y, s);
            s = fmaf(vd.z, vd.z, s); s = fmaf(vd.w, vd.w, s);
            const float S = 16384.f;
            int i0 = __builtin_amdgcn_cvt_pk_fp8_f32(va.x * S, va.y * S, 0, false);
            i0     = __builtin_amdgcn_cvt_pk_fp8_f32(va.z * S, va.w * S, i0, true);
            int i1 = __builtin_amdgcn_cvt_pk_fp8_f32(vb.x * S, vb.y * S, 0, false);
            i1     = __builtin_amdgcn_cvt_pk_fp8_f32(vb.z * S, vb.w * S, i1, true);
            int i2 = __builtin_amdgcn_cvt_pk_fp8_f32(vc.x * S, vc.y * S, 0, false);
            i2     = __builtin_amdgcn_cvt_pk_fp8_f32(vc.z * S, vc.w * S, i2, true);
            int i3 = __builtin_amdgcn_cvt_pk_fp8_f32(vd.x * S, vd.y * S, 0, false);
            i3     = __builtin_amdgcn_cvt_pk_fp8_f32(vd.z * S, vd.w * S, i3, true);
            const int slot = g ^ ((t >> 1) & 3);
            int4 q; q.x = i0; q.y = i1; q.z = i2; q.w = i3;
            *(int4*)(Eb + t * CDIM + slot * 16) = q;
        }
        biasS[t] = -8192.f * s;
    }
}

// 512 thr = 8 waves x 16 rows (128 rows/block), grid 1024: 68.3 KB LDS ->
// 2 resident blocks/CU + 2 queued -> cross-block phase overlap. fp8
// codebook staged via LINEAR async DMA (global already permuted+swizzled);
// K-loop: ONE conflict-free ds_read_b128 per j (half the LDS traffic of the
// bf16 kernel), 2 fp8 MFMAs (rate = bf16), packed-key argmax. Epilogue
// gathers exact fp32 E from global.
__global__ __launch_bounds__(512)
void vq_main(const float* __restrict__ z,
             const float* __restrict__ E,
             const unsigned char* __restrict__ Eb,
             const float* __restrict__ biasS,
             float* __restrict__ out,
             float* __restrict__ partial) {
    extern __shared__ char smem[];
    unsigned char* sEb = (unsigned char*)smem;             // 64 KB
    float (*sBiasT)[68] = (float(*)[68])(smem + 65536);    // [16][68] padded

    const int lane = threadIdx.x & 63;
    const int wave = threadIdx.x >> 6;   // 0..7
    const int lrow = lane & 15;          // row/code-col within 16-tile
    const int lgrp = lane >> 4;          // k-group 0..3

    const int n0 = blockIdx.x * 128 + wave * 16;  // wave's 16 rows
    const int b  = n0 >> 12;
    const int hw = n0 & 4095;            // 128-aligned block; +15 in batch
    const float* zb   = z   + (size_t)b * (CDIM * HWDIM);
    float*       outb = out + (size_t)b * (CDIM * HWDIM);

    // ---- stage fp8 codebook via linear async DMA: 4096 16B chunks.
    #pragma unroll
    for (int i = 0; i < 8; ++i) {
        const int cid = i * 512 + (int)threadIdx.x;
        gload_lds16(Eb + cid * 16, sEb + cid * 16);
    }
    {   // bias, transposed: sBiasT[code&15][code>>4]
        const int i = (int)threadIdx.x;
        sBiasT[i & 15][i >> 4] = biasS[i];
        const int i2 = i + 512;
        sBiasT[i2 & 15][i2 >> 4] = biasS[i2];
    }

    // A fragment: row lrow, k = 32s + 8g + j; z -> fp8 unscaled (|z|<~5).
    float szz = 0.f;
    long a0, a1;
    {
        float zv[8];
        #pragma unroll
        for (int j = 0; j < 8; ++j) {
            float v = zb[(8 * lgrp + j) * HWDIM + hw + lrow];
            szz = fmaf(v, v, szz); zv[j] = v;
        }
        int dlo = __builtin_amdgcn_cvt_pk_fp8_f32(zv[0], zv[1], 0, false);
        dlo     = __builtin_amdgcn_cvt_pk_fp8_f32(zv[2], zv[3], dlo, true);
        int dhi = __builtin_amdgcn_cvt_pk_fp8_f32(zv[4], zv[5], 0, false);
        dhi     = __builtin_amdgcn_cvt_pk_fp8_f32(zv[6], zv[7], dhi, true);
        a0 = (long)(unsigned)dlo | ((long)dhi << 32);
        #pragma unroll
        for (int j = 0; j < 8; ++j) {
            float v = zb[(32 + 8 * lgrp + j) * HWDIM + hw + lrow];
            szz = fmaf(v, v, szz); zv[j] = v;
        }
        dlo = __builtin_amdgcn_cvt_pk_fp8_f32(zv[0], zv[1], 0, false);
        dlo = __builtin_amdgcn_cvt_pk_fp8_f32(zv[2], zv[3], dlo, true);
        dhi = __builtin_amdgcn_cvt_pk_fp8_f32(zv[4], zv[5], 0, false);
        dhi = __builtin_amdgcn_cvt_pk_fp8_f32(zv[6], zv[7], dhi, true);
        a1 = (long)(unsigned)dlo | ((long)dhi << 32);
    }

    float run[4] = {-3.0e38f, -3.0e38f, -3.0e38f, -3.0e38f};

    __syncthreads();   // the ONLY barrier: DMA + bias complete

    // loop-invariant read address: slot = lgrp ^ ((lrow>>1)&3)
    const char* pa = (const char*)sEb + lrow * CDIM
                   + ((lgrp ^ ((lrow >> 1) & 3)) << 4);
    const float* pbias = &sBiasT[lrow][0];
    unsigned codev = (unsigned)lrow;

    for (int ch = 0; ch < 8; ++ch) {
        f32x4 bq0 = *(const f32x4*)(pbias);       // biases kt = ch*8+0..3
        f32x4 bq1 = *(const f32x4*)(pbias + 4);   // biases kt = ch*8+4..7
        #pragma unroll
        for (int j = 0; j < 8; ++j) {
            longx2 bb = *(const longx2*)(pa + j * 1024);   // one b128, 0-conflict
            const float bv = (j < 4) ? bq0[j] : bq1[j - 4];   // static idx
            f32x4 ci = {bv, bv, bv, bv};
            f32x4 acc = __builtin_amdgcn_mfma_f32_16x16x32_fp8_fp8(a0, bb.x, ci, 0, 0, 0);
            acc = __builtin_amdgcn_mfma_f32_16x16x32_fp8_fp8(a1, bb.y, acc, 0, 0, 0);
            const unsigned code = codev + (unsigned)(j * 16);
            #pragma unroll
            for (int r = 0; r < 4; ++r)
                run[r] = fmaxf(run[r], asf((asu(acc[r]) & 0xFFFFFC00u) | code));
        }
        pa += 8192; pbias += 8; codev += 128;
    }

    // reduce packed keys across the 16 code-columns (lrow lanes): pure max
    #pragma unroll
    for (int m = 1; m <= 8; m <<= 1)
        #pragma unroll
        for (int r = 0; r < 4; ++r)
            run[r] = fmaxf(run[r], __shfl_xor(run[r], m, 64));

    // redistribute: lane (lrow,g) holds rows 4g+r; thread for row lrow
    int idxe;
    {
        const int src = (lrow >> 2) << 4;   // lane with lgrp == lrow>>2
        float g0 = __shfl(run[0], src, 64);
        float g1 = __shfl(run[1], src, 64);
        float g2 = __shfl(run[2], src, 64);
        float g3 = __shfl(run[3], src, 64);
        float sel = (lrow & 2) ? ((lrow & 1) ? g3 : g2)
                               : ((lrow & 1) ? g1 : g0);
        idxe = (int)(asu(sel) & 1023u);
    }

    // epilogue: gather exact fp32 codebook row from global E, write out
    {
        const f32x4* ep  = (const f32x4*)(E + idxe * CDIM      + 8 * lgrp);
        const f32x4* ep2 = (const f32x4*)(E + idxe * CDIM + 32 + 8 * lgrp);
        f32x4 qa = ep[0], qb = ep[1], qc = ep2[0], qd = ep2[1];
        float* ob = outb + hw + lrow;
        #pragma unroll
        for (int j = 0; j < 4; ++j) {
            ob[(8 * lgrp + j)          * HWDIM] = qa[j];
            ob[(8 * lgrp + 4 + j)      * HWDIM] = qb[j];
            ob[(32 + 8 * lgrp + j)     * HWDIM] = qc[j];
            ob[(32 + 8 * lgrp + 4 + j) * HWDIM] = qd[j];
        }
    }

    // loss partial: sum z^2 + sum over rows of d_min, d_min = -2^-13 * S
    float dsum = run[0] + run[1] + run[2] + run[3];
    float contrib = szz + ((lrow == 0) ? (-1.220703125e-4f * dsum) : 0.f);
    #pragma unroll
    for (int m = 32; m >= 1; m >>= 1) contrib += __shfl_xor(contrib, m, 64);
    if (lane == 0) partial[blockIdx.x * 8 + wave] = contrib;
}

__global__ __launch_bounds__(1024)
void vq_fin(const float* __restrict__ partial,
            float* __restrict__ out) {
    __shared__ float red[16];
    const int tid = threadIdx.x;   // 1024 threads
    float s = 0.f;
    #pragma unroll
    for (int i = 0; i < NPART / 1024; ++i) s += partial[i * 1024 + tid];
    #pragma unroll
    for (int m = 32; m >= 1; m >>= 1) s += __shfl_xor(s, m, 64);
    if ((tid & 63) == 0) red[tid >> 6] = s;
    __syncthreads();
    if (tid == 0) {
        float tot = 0.f;
        #pragma unroll
        for (int w = 0; w < 16; ++w) tot += red[w];
        out[NELEM] = 1.25f * tot / (float)NELEM;
    }
}

extern "C" void kernel_launch(void* const* d_in, const int* in_sizes, int n_in,
                              void* d_out, int out_size, void* d_ws, size_t ws_size,
                              hipStream_t stream) {
    const float* z = (const float*)d_in[0];
    const float* E = (const float*)d_in[1];
    float* out = (float*)d_out;

    unsigned char* Eb = (unsigned char*)d_ws;                   // 64 KB
    float* biasS      = (float*)((char*)d_ws + 65536);          // 4 KB
    float* partial    = (float*)((char*)d_ws + 65536 + 4096);   // 32 KB

    // allow >64 KB dynamic LDS (host-side attribute; graph-capture safe)
    hipFuncSetAttribute((const void*)vq_main,
                        hipFuncAttributeMaxDynamicSharedMemorySize, LDSSZ);

    vq_prep<<<4, 256, 0, stream>>>(E, Eb, biasS);
    vq_main<<<NBLOCK, 512, LDSSZ, stream>>>(z, E, Eb, biasS, out, partial);
    vq_fin<<<1, 1024, 0, stream>>>(partial, out);
}

// Round 21
// 32.845 us; speedup vs baseline: 1.5257x; 1.0506x over previous
//
#include <hip/hip_runtime.h>
#include <hip/hip_bf16.h>

#define CDIM   64
#define HWDIM  4096
#define NCODES 1024
#define NELEM  8388608   // 32*64*64*64 = N*C
#define NBLOCK 512       // 131072 rows / 256 rows-per-block; 2 resident/CU
#define NPART  (NBLOCK * 8)
#define LDSSZ  (65536 + 16 * 68 * 4)   // 64 KB fp8 codebook + padded bias

typedef float f32x4 __attribute__((ext_vector_type(4)));
typedef long  longx2 __attribute__((ext_vector_type(2)));

__device__ __forceinline__ unsigned asu(float f) {
    union { float f; unsigned u; } v; v.f = f; return v.u;
}
__device__ __forceinline__ float asf(unsigned u) {
    union { unsigned u; float f; } v; v.u = u; return v.f;
}
__device__ __forceinline__ void gload_lds16(const void* g, void* l) {
    __builtin_amdgcn_global_load_lds(
        (const __attribute__((address_space(1))) void*)g,
        (__attribute__((address_space(3))) void*)l, 16, 0, 0);
}

// prep (R20, unchanged): Eb = fp8_e4m3(16384*E), pre-permuted + pre-swizzled
// per 64B row: slot s = g ^ ((row>>1)&3) holds the 16B lane-group g consumes
// ([0..7]=fp8(e[8g..8g+7]), [8..15]=fp8(e[32+8g..+7])). Main's DMA is LINEAR
// and its ds_read_b128 is bank-conflict-free (verified R20: conflicts
// 1.27e7 -> ~0, dur 50 -> 34.5). biasS = -8192*||e||^2.
__global__ void vq_prep(const float* __restrict__ E,
                        unsigned char* __restrict__ Eb,
                        float* __restrict__ biasS) {
    int t = blockIdx.x * blockDim.x + threadIdx.x;   // one thread per code
    if (t < NCODES) {
        const float4* ev = (const float4*)(E + t * CDIM);
        float s = 0.f;
        #pragma unroll
        for (int g = 0; g < 4; ++g) {
            float4 va = ev[2 * g], vb = ev[2 * g + 1];       // k = 8g..8g+7
            float4 vc = ev[8 + 2 * g], vd = ev[9 + 2 * g];   // k = 32+8g..+7
            s = fmaf(va.x, va.x, s); s = fmaf(va.y, va.y, s);
            s = fmaf(va.z, va.z, s); s = fmaf(va.w, va.w, s);
            s = fmaf(vb.x, vb.x, s); s = fmaf(vb.y, vb.y, s);
            s = fmaf(vb.z, vb.z, s); s = fmaf(vb.w, vb.w, s);
            s = fmaf(vc.x, vc.x, s); s = fmaf(vc.y, vc.y, s);
            s = fmaf(vc.z, vc.z, s); s = fmaf(vc.w, vc.w, s);
            s = fmaf(vd.x, vd.x, s); s = fmaf(vd.y, vd.y, s);
            s = fmaf(vd.z, vd.z, s); s = fmaf(vd.w, vd.w, s);
            const float S = 16384.f;
            int i0 = __builtin_amdgcn_cvt_pk_fp8_f32(va.x * S, va.y * S, 0, false);
            i0     = __builtin_amdgcn_cvt_pk_fp8_f32(va.z * S, va.w * S, i0, true);
            int i1 = __builtin_amdgcn_cvt_pk_fp8_f32(vb.x * S, vb.y * S, 0, false);
            i1     = __builtin_amdgcn_cvt_pk_fp8_f32(vb.z * S, vb.w * S, i1, true);
            int i2 = __builtin_amdgcn_cvt_pk_fp8_f32(vc.x * S, vc.y * S, 0, false);
            i2     = __builtin_amdgcn_cvt_pk_fp8_f32(vc.z * S, vc.w * S, i2, true);
            int i3 = __builtin_amdgcn_cvt_pk_fp8_f32(vd.x * S, vd.y * S, 0, false);
            i3     = __builtin_amdgcn_cvt_pk_fp8_f32(vd.z * S, vd.w * S, i3, true);
            const int slot = g ^ ((t >> 1) & 3);
            int4 q; q.x = i0; q.y = i1; q.z = i2; q.w = i3;
            *(int4*)(Eb + t * CDIM + slot * 16) = q;
        }
        biasS[t] = -8192.f * s;
    }
}

// 512 thr = 8 waves x 32 ROWS (2 MFMA row-tiles/wave), 256 rows/block,
// grid 512: still 2 resident blocks/CU (68.3 KB LDS) = 16 waves/CU, but
// per-CU LDS codebook re-read HALVES (1 MB per 256 rows -> per 512) and one
// shared ds_read_b128 now feeds 4 MFMAs. fp8 A-state is light (8 VGPRs for
// both tiles) so this fits the 52-VGPR/512-thr cap that killed R12/R17.
__global__ __launch_bounds__(512)
void vq_main(const float* __restrict__ z,
             const float* __restrict__ E,
             const unsigned char* __restrict__ Eb,
             const float* __restrict__ biasS,
             float* __restrict__ out,
             float* __restrict__ partial) {
    extern __shared__ char smem[];
    unsigned char* sEb = (unsigned char*)smem;             // 64 KB
    float (*sBiasT)[68] = (float(*)[68])(smem + 65536);    // [16][68] padded

    const int lane = threadIdx.x & 63;
    const int wave = threadIdx.x >> 6;   // 0..7
    const int lrow = lane & 15;          // row/code-col within 16-tile
    const int lgrp = lane >> 4;          // k-group 0..3

    const int n0 = blockIdx.x * 256 + wave * 32;  // wave's 32 rows
    const int b  = n0 >> 12;
    const int hw = n0 & 4095;            // 256-aligned block; +31 in batch
    const float* zb   = z   + (size_t)b * (CDIM * HWDIM);
    float*       outb = out + (size_t)b * (CDIM * HWDIM);

    // ---- stage fp8 codebook via linear async DMA: 4096 16B chunks.
    #pragma unroll
    for (int i = 0; i < 8; ++i) {
        const int cid = i * 512 + (int)threadIdx.x;
        gload_lds16(Eb + cid * 16, sEb + cid * 16);
    }
    {   // bias, transposed: sBiasT[code&15][code>>4]
        const int i = (int)threadIdx.x;
        sBiasT[i & 15][i >> 4] = biasS[i];
        const int i2 = i + 512;
        sBiasT[i2 & 15][i2 >> 4] = biasS[i2];
    }

    // A fragments for 2 tiles: tile t rows n0+16t+lrow; z -> fp8 unscaled.
    float szz = 0.f;
    long a00, a01, a10, a11;
    {
        float zv[8];
        #pragma unroll
        for (int t = 0; t < 2; ++t) {
            #pragma unroll
            for (int j = 0; j < 8; ++j) {
                float v = zb[(8 * lgrp + j) * HWDIM + hw + t * 16 + lrow];
                szz = fmaf(v, v, szz); zv[j] = v;
            }
            int dlo = __builtin_amdgcn_cvt_pk_fp8_f32(zv[0], zv[1], 0, false);
            dlo     = __builtin_amdgcn_cvt_pk_fp8_f32(zv[2], zv[3], dlo, true);
            int dhi = __builtin_amdgcn_cvt_pk_fp8_f32(zv[4], zv[5], 0, false);
            dhi     = __builtin_amdgcn_cvt_pk_fp8_f32(zv[6], zv[7], dhi, true);
            long lo = (long)(unsigned)dlo | ((long)dhi << 32);
            #pragma unroll
            for (int j = 0; j < 8; ++j) {
                float v = zb[(32 + 8 * lgrp + j) * HWDIM + hw + t * 16 + lrow];
                szz = fmaf(v, v, szz); zv[j] = v;
            }
            dlo = __builtin_amdgcn_cvt_pk_fp8_f32(zv[0], zv[1], 0, false);
            dlo = __builtin_amdgcn_cvt_pk_fp8_f32(zv[2], zv[3], dlo, true);
            dhi = __builtin_amdgcn_cvt_pk_fp8_f32(zv[4], zv[5], 0, false);
            dhi = __builtin_amdgcn_cvt_pk_fp8_f32(zv[6], zv[7], dhi, true);
            long hi = (long)(unsigned)dlo | ((long)dhi << 32);
            if (t == 0) { a00 = lo; a01 = hi; }
            else        { a10 = lo; a11 = hi; }
        }
    }

    float run[2][4];
    #pragma unroll
    for (int t = 0; t < 2; ++t)
        #pragma unroll
        for (int r = 0; r < 4; ++r) run[t][r] = -3.0e38f;

    __syncthreads();   // the ONLY barrier: DMA + bias complete

    // loop-invariant read address: slot = lgrp ^ ((lrow>>1)&3)
    const char* pa = (const char*)sEb + lrow * CDIM
                   + ((lgrp ^ ((lrow >> 1) & 3)) << 4);
    const float* pbias = &sBiasT[lrow][0];
    unsigned codev = (unsigned)lrow;

    for (int ch = 0; ch < 8; ++ch) {
        f32x4 bq0 = *(const f32x4*)(pbias);       // biases kt = ch*8+0..3
        f32x4 bq1 = *(const f32x4*)(pbias + 4);   // biases kt = ch*8+4..7
        #pragma unroll
        for (int j = 0; j < 8; ++j) {
            longx2 bb = *(const longx2*)(pa + j * 1024);   // one b128, 0-conflict
            const float bv = (j < 4) ? bq0[j] : bq1[j - 4];   // static idx
            f32x4 ci = {bv, bv, bv, bv};
            f32x4 ac0 = __builtin_amdgcn_mfma_f32_16x16x32_fp8_fp8(a00, bb.x, ci, 0, 0, 0);
            ac0 = __builtin_amdgcn_mfma_f32_16x16x32_fp8_fp8(a01, bb.y, ac0, 0, 0, 0);
            f32x4 ac1 = __builtin_amdgcn_mfma_f32_16x16x32_fp8_fp8(a10, bb.x, ci, 0, 0, 0);
            ac1 = __builtin_amdgcn_mfma_f32_16x16x32_fp8_fp8(a11, bb.y, ac1, 0, 0, 0);
            const unsigned code = codev + (unsigned)(j * 16);
            #pragma unroll
            for (int r = 0; r < 4; ++r) {
                run[0][r] = fmaxf(run[0][r], asf((asu(ac0[r]) & 0xFFFFFC00u) | code));
                run[1][r] = fmaxf(run[1][r], asf((asu(ac1[r]) & 0xFFFFFC00u) | code));
            }
        }
        pa += 8192; pbias += 8; codev += 128;
    }

    // reduce packed keys across the 16 code-columns (lrow lanes): pure max
    #pragma unroll
    for (int m = 1; m <= 8; m <<= 1)
        #pragma unroll
        for (int t = 0; t < 2; ++t)
            #pragma unroll
            for (int r = 0; r < 4; ++r)
                run[t][r] = fmaxf(run[t][r], __shfl_xor(run[t][r], m, 64));

    // redistribute: lane (lrow,g) holds rows 4g+r of each tile
    int idxe[2];
    #pragma unroll
    for (int t = 0; t < 2; ++t) {
        const int src = (lrow >> 2) << 4;   // lane with lgrp == lrow>>2
        float g0 = __shfl(run[t][0], src, 64);
        float g1 = __shfl(run[t][1], src, 64);
        float g2 = __shfl(run[t][2], src, 64);
        float g3 = __shfl(run[t][3], src, 64);
        float sel = (lrow & 2) ? ((lrow & 1) ? g3 : g2)
                               : ((lrow & 1) ? g1 : g0);
        idxe[t] = (int)(asu(sel) & 1023u);
    }

    // epilogue: gather exact fp32 codebook rows from global E, write out
    #pragma unroll
    for (int t = 0; t < 2; ++t) {
        const int idxr = idxe[t];
        const f32x4* ep  = (const f32x4*)(E + idxr * CDIM      + 8 * lgrp);
        const f32x4* ep2 = (const f32x4*)(E + idxr * CDIM + 32 + 8 * lgrp);
        f32x4 qa = ep[0], qb = ep[1], qc = ep2[0], qd = ep2[1];
        float* ob = outb + hw + t * 16 + lrow;
        #pragma unroll
        for (int j = 0; j < 4; ++j) {
            ob[(8 * lgrp + j)          * HWDIM] = qa[j];
            ob[(8 * lgrp + 4 + j)      * HWDIM] = qb[j];
            ob[(32 + 8 * lgrp + j)     * HWDIM] = qc[j];
            ob[(32 + 8 * lgrp + 4 + j) * HWDIM] = qd[j];
        }
    }

    // loss partial: sum z^2 + sum over rows of d_min, d_min = -2^-13 * S
    float dsum = 0.f;
    #pragma unroll
    for (int t = 0; t < 2; ++t)
        #pragma unroll
        for (int r = 0; r < 4; ++r) dsum += run[t][r];
    float contrib = szz + ((lrow == 0) ? (-1.220703125e-4f * dsum) : 0.f);
    #pragma unroll
    for (int m = 32; m >= 1; m >>= 1) contrib += __shfl_xor(contrib, m, 64);
    if (lane == 0) partial[blockIdx.x * 8 + wave] = contrib;
}

__global__ __launch_bounds__(1024)
void vq_fin(const float* __restrict__ partial,
            float* __restrict__ out) {
    __shared__ float red[16];
    const int tid = threadIdx.x;   // 1024 threads
    float s = 0.f;
    #pragma unroll
    for (int i = 0; i < NPART / 1024; ++i) s += partial[i * 1024 + tid];
    #pragma unroll
    for (int m = 32; m >= 1; m >>= 1) s += __shfl_xor(s, m, 64);
    if ((tid & 63) == 0) red[tid >> 6] = s;
    __syncthreads();
    if (tid == 0) {
        float tot = 0.f;
        #pragma unroll
        for (int w = 0; w < 16; ++w) tot += red[w];
        out[NELEM] = 1.25f * tot / (float)NELEM;
    }
}

extern "C" void kernel_launch(void* const* d_in, const int* in_sizes, int n_in,
                              void* d_out, int out_size, void* d_ws, size_t ws_size,
                              hipStream_t stream) {
    const float* z = (const float*)d_in[0];
    const float* E = (const float*)d_in[1];
    float* out = (float*)d_out;

    unsigned char* Eb = (unsigned char*)d_ws;                   // 64 KB
    float* biasS      = (float*)((char*)d_ws + 65536);          // 4 KB
    float* partial    = (float*)((char*)d_ws + 65536 + 4096);   // 16 KB

    // allow >64 KB dynamic LDS (host-side attribute; graph-capture safe)
    hipFuncSetAttribute((const void*)vq_main,
                        hipFuncAttributeMaxDynamicSharedMemorySize, LDSSZ);

    vq_prep<<<4, 256, 0, stream>>>(E, Eb, biasS);
    vq_main<<<NBLOCK, 512, LDSSZ, stream>>>(z, E, Eb, biasS, out, partial);
    vq_fin<<<1, 1024, 0, stream>>>(partial, out);
}